// Round 9
// baseline (271.701 us; speedup 1.0000x reference)
//
#include <hip/hip_runtime.h>

#define ITERS 20

// TWO independent Sinkhorn chains interleaved per wave (matrices 2w, 2w+1).
// Rationale (R0-R8 profiling): all 1-matrix/wave variants pin aggregate VALU
// busy at ~58-60us vs a ~40us issue model — short stall holes (DPP/permlane
// hazards, 1/4-rate TRANS rcp) that resident waves fail to fill because they
// phase-align. A second in-wave chain provides guaranteed independent
// instructions for every hole: chain B's matvec issues under chain A's
// reduce/rcp latency. 4096 waves = 4 work-waves/SIMD, 2 resident (at ~190
// VGPRs under launch_bounds(256,2)) -> generation turnover overlaps gen-2
// loads with gen-1 compute/stores.
//
// Per chain: lane (bi,bj) owns the 8x8 sub-block rows [8bi,8bi+8), cols
// [8bj,8bj+8) = 64 fp32 E regs. Sinkhorn iterate M = E .* (u v^T): only u,v
// update; E stays in registers. Scalar fp32 math (pk/dot2/mix proven
// rate-neutral or worse). u = rcp(p) (EPS=1e-9 dropped: ~1e-9 relative,
// orders below tolerance). Cross-lane reduces all-VALU: fused DPP adds for
// xor1/xor2/xor7(=4)/xor8, permlane16/32_swap for xor16/32.

template <int CTRL>
__device__ __forceinline__ float dpp_add(float x) {
    int yi = __builtin_amdgcn_update_dpp(0, __float_as_int(x), CTRL, 0xf, 0xf, true);
    return x + __int_as_float(yi);
}

#if __has_builtin(__builtin_amdgcn_permlane16_swap)
// identical inputs: r0+r1 == xor16 butterfly all-reduce, pure VALU
__device__ __forceinline__ float xadd16(float x) {
    unsigned u = __float_as_uint(x);
    auto r = __builtin_amdgcn_permlane16_swap(u, u, false, false);
    return __uint_as_float(r[0]) + __uint_as_float(r[1]);
}
#else
__device__ __forceinline__ float xadd16(float x) {
    return x + __int_as_float(__builtin_amdgcn_ds_swizzle(__float_as_int(x), 0x401F));
}
#endif

#if __has_builtin(__builtin_amdgcn_permlane32_swap)
__device__ __forceinline__ float xadd32(float x) {
    unsigned u = __float_as_uint(x);
    auto r = __builtin_amdgcn_permlane32_swap(u, u, false, false);
    return __uint_as_float(r[0]) + __uint_as_float(r[1]);
}
#else
__device__ __forceinline__ float xadd32(float x) {
    return x + __shfl_xor(x, 32, 64);
}
#endif

__global__ __launch_bounds__(256, 2) void sinkhorn_kernel(
        const float* __restrict__ x, float* __restrict__ out, int nmat) {
    const int lane = threadIdx.x & 63;
    const int wave = threadIdx.x >> 6;
    const int wid  = blockIdx.x * 4 + wave;
    const int matA = wid * 2;
    if (matA >= nmat) return;
    const int matB = matA + 1;
    const bool hasB = (matB < nmat);
    const int bi = lane >> 3;   // block-row 0..7 (lane bits 3-5)
    const int bj = lane & 7;    // block-col 0..7 (lane bits 0-2)

    const float4* __restrict__ xa = (const float4*)(x + (size_t)matA * 4096);
    const float4* __restrict__ xb = (const float4*)(x + (size_t)(hasB ? matB : matA) * 4096);

    // Load both 8x8 blocks (interleaved), exp in place.
    float A[8][8], B[8][8];
    #pragma unroll
    for (int r = 0; r < 8; ++r) {
        float4 alo = xa[(8 * bi + r) * 16 + 2 * bj + 0];
        float4 ahi = xa[(8 * bi + r) * 16 + 2 * bj + 1];
        float4 blo = xb[(8 * bi + r) * 16 + 2 * bj + 0];
        float4 bhi = xb[(8 * bi + r) * 16 + 2 * bj + 1];
        A[r][0] = __expf(alo.x); A[r][1] = __expf(alo.y);
        A[r][2] = __expf(alo.z); A[r][3] = __expf(alo.w);
        A[r][4] = __expf(ahi.x); A[r][5] = __expf(ahi.y);
        A[r][6] = __expf(ahi.z); A[r][7] = __expf(ahi.w);
        B[r][0] = __expf(blo.x); B[r][1] = __expf(blo.y);
        B[r][2] = __expf(blo.z); B[r][3] = __expf(blo.w);
        B[r][4] = __expf(bhi.x); B[r][5] = __expf(bhi.y);
        B[r][6] = __expf(bhi.z); B[r][7] = __expf(bhi.w);
    }

    float ua[8], va[8], ub[8], vb[8];
    #pragma unroll
    for (int i = 0; i < 8; ++i) { ua[i] = 1.0f; va[i] = 1.0f; ub[i] = 1.0f; vb[i] = 1.0f; }

    for (int it = 0; it < ITERS; ++it) {
        // ---- row phase (both chains): p_i = sum_j E[i,j] v_j ; u = rcp(p) ----
        float pa[8], pb[8];
        #pragma unroll
        for (int r = 0; r < 8; ++r) {
            float sae = A[r][0] * va[0], sao = A[r][1] * va[1];
            float sbe = B[r][0] * vb[0], sbo = B[r][1] * vb[1];
            sae = fmaf(A[r][2], va[2], sae); sbe = fmaf(B[r][2], vb[2], sbe);
            sao = fmaf(A[r][3], va[3], sao); sbo = fmaf(B[r][3], vb[3], sbo);
            sae = fmaf(A[r][4], va[4], sae); sbe = fmaf(B[r][4], vb[4], sbe);
            sao = fmaf(A[r][5], va[5], sao); sbo = fmaf(B[r][5], vb[5], sbo);
            sae = fmaf(A[r][6], va[6], sae); sbe = fmaf(B[r][6], vb[6], sbe);
            sao = fmaf(A[r][7], va[7], sao); sbo = fmaf(B[r][7], vb[7], sbo);
            pa[r] = sae + sao;
            pb[r] = sbe + sbo;
        }
        // all-reduce across the 8 bj lanes (lane bits 0-2), chains interleaved
        #pragma unroll
        for (int r = 0; r < 8; ++r) { pa[r] = dpp_add<0xB1>(pa[r]);  pb[r] = dpp_add<0xB1>(pb[r]); }
        #pragma unroll
        for (int r = 0; r < 8; ++r) { pa[r] = dpp_add<0x4E>(pa[r]);  pb[r] = dpp_add<0x4E>(pb[r]); }
        #pragma unroll
        for (int r = 0; r < 8; ++r) { pa[r] = dpp_add<0x141>(pa[r]); pb[r] = dpp_add<0x141>(pb[r]); }
        #pragma unroll
        for (int r = 0; r < 8; ++r) {
            ua[r] = __builtin_amdgcn_rcpf(pa[r]);
            ub[r] = __builtin_amdgcn_rcpf(pb[r]);
        }

        // ---- col phase (both chains): q_j = sum_i E[i,j] u_i ; v = rcp(q) ----
        float qa[8], qb[8];
        #pragma unroll
        for (int c = 0; c < 8; ++c) {
            float sae = A[0][c] * ua[0], sao = A[1][c] * ua[1];
            float sbe = B[0][c] * ub[0], sbo = B[1][c] * ub[1];
            sae = fmaf(A[2][c], ua[2], sae); sbe = fmaf(B[2][c], ub[2], sbe);
            sao = fmaf(A[3][c], ua[3], sao); sbo = fmaf(B[3][c], ub[3], sbo);
            sae = fmaf(A[4][c], ua[4], sae); sbe = fmaf(B[4][c], ub[4], sbe);
            sao = fmaf(A[5][c], ua[5], sao); sbo = fmaf(B[5][c], ub[5], sbo);
            sae = fmaf(A[6][c], ua[6], sae); sbe = fmaf(B[6][c], ub[6], sbe);
            sao = fmaf(A[7][c], ua[7], sao); sbo = fmaf(B[7][c], ub[7], sbo);
            qa[c] = sae + sao;
            qb[c] = sbe + sbo;
        }
        // all-reduce across the 8 bi lanes (lane bits 3-5), chains interleaved
        #pragma unroll
        for (int c = 0; c < 8; ++c) { qa[c] = dpp_add<0x128>(qa[c]); qb[c] = dpp_add<0x128>(qb[c]); }
        #pragma unroll
        for (int c = 0; c < 8; ++c) { qa[c] = xadd16(qa[c]);         qb[c] = xadd16(qb[c]); }
        #pragma unroll
        for (int c = 0; c < 8; ++c) { qa[c] = xadd32(qa[c]);         qb[c] = xadd32(qb[c]); }
        #pragma unroll
        for (int c = 0; c < 8; ++c) {
            va[c] = __builtin_amdgcn_rcpf(qa[c]);
            vb[c] = __builtin_amdgcn_rcpf(qb[c]);
        }
    }

    // ---- epilogue: out = E .* (u v^T), both chains ----
    float4* __restrict__ oa = (float4*)(out + (size_t)matA * 4096);
    #pragma unroll
    for (int r = 0; r < 8; ++r) {
        float ur = ua[r];
        float4 lo, hi;
        lo.x = A[r][0] * ur * va[0]; lo.y = A[r][1] * ur * va[1];
        lo.z = A[r][2] * ur * va[2]; lo.w = A[r][3] * ur * va[3];
        hi.x = A[r][4] * ur * va[4]; hi.y = A[r][5] * ur * va[5];
        hi.z = A[r][6] * ur * va[6]; hi.w = A[r][7] * ur * va[7];
        oa[(8 * bi + r) * 16 + 2 * bj + 0] = lo;
        oa[(8 * bi + r) * 16 + 2 * bj + 1] = hi;
    }
    if (hasB) {
        float4* __restrict__ ob = (float4*)(out + (size_t)matB * 4096);
        #pragma unroll
        for (int r = 0; r < 8; ++r) {
            float ur = ub[r];
            float4 lo, hi;
            lo.x = B[r][0] * ur * vb[0]; lo.y = B[r][1] * ur * vb[1];
            lo.z = B[r][2] * ur * vb[2]; lo.w = B[r][3] * ur * vb[3];
            hi.x = B[r][4] * ur * vb[4]; hi.y = B[r][5] * ur * vb[5];
            hi.z = B[r][6] * ur * vb[6]; hi.w = B[r][7] * ur * vb[7];
            ob[(8 * bi + r) * 16 + 2 * bj + 0] = lo;
            ob[(8 * bi + r) * 16 + 2 * bj + 1] = hi;
        }
    }
}

extern "C" void kernel_launch(void* const* d_in, const int* in_sizes, int n_in,
                              void* d_out, int out_size, void* d_ws, size_t ws_size,
                              hipStream_t stream) {
    const float* x = (const float*)d_in[0];
    float* out = (float*)d_out;
    const int nmat = in_sizes[0] / 4096;          // 8192 matrices of 64x64
    const int waves = (nmat + 1) / 2;             // 2 matrices per wave
    const int blocks = (waves + 3) / 4;           // 4 waves per block -> 1024 blocks
    sinkhorn_kernel<<<blocks, 256, 0, stream>>>(x, out, nmat);
}

// Round 10
// 262.042 us; speedup vs baseline: 1.0369x; 1.0369x over previous
//
#include <hip/hip_runtime.h>

#define ITERS 20
#define EPS 1e-9f
#define MPW 4   // matrices per wave, streamed through the LDS prefetch slab

typedef float v2f __attribute__((ext_vector_type(2)));
typedef unsigned int u32;

// Persistent-wave Sinkhorn with ZERO-VGPR prefetch: while a wave computes
// matrix m out of registers, matrix m+1 DMAs into its private 16KB LDS slab
// via global_load_lds (no register cost -> occupancy unchanged, unlike the
// failed R8/R9 register-prefetch variants). Compute body is bit-identical to
// the verified R6 kernel (pk-asm matvecs, DPP/permlane reduces, u=rcp(p+eps)).
//
// Profiling motivation: R6 dur 94.5us = busy 60us + ~35us of EXPOSED memory
// phases (avg HBM 2.0 TB/s << 6.3 achievable; VALU idle during load/store
// bursts). This round changes ONLY data movement to overlap those phases.

template <int CTRL>
__device__ __forceinline__ float dpp_add(float x) {
    int yi = __builtin_amdgcn_update_dpp(0, __float_as_int(x), CTRL, 0xf, 0xf, true);
    return x + __int_as_float(yi);
}

#if __has_builtin(__builtin_amdgcn_permlane16_swap)
// identical inputs: r0+r1 == xor16 butterfly all-reduce, pure VALU
__device__ __forceinline__ float xadd16(float x) {
    unsigned u = __float_as_uint(x);
    auto r = __builtin_amdgcn_permlane16_swap(u, u, false, false);
    return __uint_as_float(r[0]) + __uint_as_float(r[1]);
}
#else
__device__ __forceinline__ float xadd16(float x) {
    return x + __int_as_float(__builtin_amdgcn_ds_swizzle(__float_as_int(x), 0x401F));
}
#endif

#if __has_builtin(__builtin_amdgcn_permlane32_swap)
__device__ __forceinline__ float xadd32(float x) {
    unsigned u = __float_as_uint(x);
    auto r = __builtin_amdgcn_permlane32_swap(u, u, false, false);
    return __uint_as_float(r[0]) + __uint_as_float(r[1]);
}
#else
__device__ __forceinline__ float xadd32(float x) {
    return x + __shfl_xor(x, 32, 64);
}
#endif

// ---- pinned packed-fp32 ops (R6-verified) ----
__device__ __forceinline__ v2f pk_mul(v2f a, v2f b) {
    v2f d; asm("v_pk_mul_f32 %0, %1, %2" : "=v"(d) : "v"(a), "v"(b)); return d;
}
__device__ __forceinline__ v2f pk_fma(v2f a, v2f b, v2f c) {
    v2f d; asm("v_pk_fma_f32 %0, %1, %2, %3" : "=v"(d) : "v"(a), "v"(b), "v"(c)); return d;
}
__device__ __forceinline__ v2f pk_add(v2f a, v2f b) {
    v2f d; asm("v_pk_add_f32 %0, %1, %2" : "=v"(d) : "v"(a), "v"(b)); return d;
}
__device__ __forceinline__ v2f pk_fma_bl(v2f a, v2f u2, v2f c) {
    v2f d;
    asm("v_pk_fma_f32 %0, %1, %2, %3 op_sel:[0,0,0] op_sel_hi:[1,0,1]"
        : "=v"(d) : "v"(a), "v"(u2), "v"(c));
    return d;
}
__device__ __forceinline__ v2f pk_fma_bh(v2f a, v2f u2, v2f c) {
    v2f d;
    asm("v_pk_fma_f32 %0, %1, %2, %3 op_sel:[0,1,0] op_sel_hi:[1,1,1]"
        : "=v"(d) : "v"(a), "v"(u2), "v"(c));
    return d;
}
__device__ __forceinline__ v2f pk_mul_bl(v2f a, v2f u2) {
    v2f d;
    asm("v_pk_mul_f32 %0, %1, %2 op_sel:[0,0] op_sel_hi:[1,0]"
        : "=v"(d) : "v"(a), "v"(u2));
    return d;
}
__device__ __forceinline__ v2f pk_mul_bh(v2f a, v2f u2) {
    v2f d;
    asm("v_pk_mul_f32 %0, %1, %2 op_sel:[0,1] op_sel_hi:[1,1]"
        : "=v"(d) : "v"(a), "v"(u2));
    return d;
}

// Async DMA of one 16KB matrix into this wave's LDS slab. Zero VGPR cost.
// LDS dest is wave-uniform base + lane*16; global src is per-lane.
__device__ __forceinline__ void dma_mat(float* lds, const float* gsrc, int lane) {
#if __has_builtin(__builtin_amdgcn_global_load_lds)
    #pragma unroll
    for (int k = 0; k < 16; ++k) {
        __builtin_amdgcn_global_load_lds(
            (const __attribute__((address_space(1))) u32*)(gsrc + k * 256 + lane * 4),
            (__attribute__((address_space(3))) u32*)(lds + k * 256),
            16, 0, 0);
    }
#else
    #pragma unroll
    for (int k = 0; k < 16; ++k)
        ((float4*)lds)[k * 64 + lane] = ((const float4*)gsrc)[k * 64 + lane];
#endif
}

__global__ __launch_bounds__(128, 2) void sinkhorn_kernel(
        const float* __restrict__ x, float* __restrict__ out, int nmat) {
    __shared__ float lbuf[2][4096];   // 32 KB: one 16KB slab per wave

    const int lane = threadIdx.x & 63;
    const int wave = threadIdx.x >> 6;
    const int wid  = blockIdx.x * 2 + wave;
    const int mat0 = wid * MPW;
    if (mat0 >= nmat) return;
    const int bi = lane >> 3;   // block-row 0..7 (lane bits 3-5)
    const int bj = lane & 7;    // block-col 0..7 (lane bits 0-2)
    float* lw = lbuf[wave];

    // prologue: DMA matrix mat0
    dma_mat(lw, x + (size_t)mat0 * 4096, lane);

    for (int m = 0; m < MPW; ++m) {
        const int mat = mat0 + m;
        if (mat >= nmat) break;               // wave-uniform

        // DMA of matrix m complete (also drains prior stores)
        asm volatile("s_waitcnt vmcnt(0)" ::: "memory");

        // LDS -> registers, exp
        v2f b2[8][4];
        const float4* ls = (const float4*)lw;
        #pragma unroll
        for (int r = 0; r < 8; ++r) {
            float4 lo = ls[(8 * bi + r) * 16 + 2 * bj + 0];
            float4 hi = ls[(8 * bi + r) * 16 + 2 * bj + 1];
            b2[r][0] = (v2f){__expf(lo.x), __expf(lo.y)};
            b2[r][1] = (v2f){__expf(lo.z), __expf(lo.w)};
            b2[r][2] = (v2f){__expf(hi.x), __expf(hi.y)};
            b2[r][3] = (v2f){__expf(hi.z), __expf(hi.w)};
        }
        // all LDS reads retired before the DMA below overwrites the slab
        asm volatile("s_waitcnt lgkmcnt(0)" ::: "memory");

        // prefetch matrix m+1 while we compute matrix m
        if (m + 1 < MPW && mat + 1 < nmat)
            dma_mat(lw, x + (size_t)(mat + 1) * 4096, lane);

        // ---- 20 Sinkhorn iterations (R6-verified body) ----
        v2f uu2[4], vv2[4];
        #pragma unroll
        for (int i = 0; i < 4; ++i) {
            uu2[i] = (v2f){1.0f, 1.0f};
            vv2[i] = (v2f){1.0f, 1.0f};
        }

        for (int it = 0; it < ITERS; ++it) {
            // row phase: p_i = sum_j E[i,j] v_j ; u_i = rcp(p_i + eps)
            float p[8];
            #pragma unroll
            for (int r = 0; r < 8; ++r) {
                v2f s2 = pk_mul(b2[r][0], vv2[0]);
                s2 = pk_fma(b2[r][1], vv2[1], s2);
                s2 = pk_fma(b2[r][2], vv2[2], s2);
                s2 = pk_fma(b2[r][3], vv2[3], s2);
                p[r] = s2.x + s2.y;
            }
            #pragma unroll
            for (int r = 0; r < 8; ++r) p[r] = dpp_add<0xB1>(p[r]);   // xor1
            #pragma unroll
            for (int r = 0; r < 8; ++r) p[r] = dpp_add<0x4E>(p[r]);   // xor2
            #pragma unroll
            for (int r = 0; r < 8; ++r) p[r] = dpp_add<0x141>(p[r]);  // xor7
            #pragma unroll
            for (int k = 0; k < 4; ++k) {
                uu2[k].x = __builtin_amdgcn_rcpf(p[2 * k + 0] + EPS);
                uu2[k].y = __builtin_amdgcn_rcpf(p[2 * k + 1] + EPS);
            }

            // col phase: q_j = sum_i E[i,j] u_i ; v_j = rcp(q_j + eps)
            v2f qe[4], qo[4];
            #pragma unroll
            for (int c = 0; c < 4; ++c) {
                qe[c] = pk_mul_bl(b2[0][c], uu2[0]);
                qo[c] = pk_mul_bh(b2[1][c], uu2[0]);
            }
            #pragma unroll
            for (int k = 1; k < 4; ++k) {
                #pragma unroll
                for (int c = 0; c < 4; ++c) {
                    qe[c] = pk_fma_bl(b2[2 * k + 0][c], uu2[k], qe[c]);
                    qo[c] = pk_fma_bh(b2[2 * k + 1][c], uu2[k], qo[c]);
                }
            }
            float q[8];
            #pragma unroll
            for (int c = 0; c < 4; ++c) {
                v2f s2 = pk_add(qe[c], qo[c]);
                q[2 * c + 0] = s2.x;
                q[2 * c + 1] = s2.y;
            }
            #pragma unroll
            for (int c = 0; c < 8; ++c) q[c] = dpp_add<0x128>(q[c]);  // xor8
            #pragma unroll
            for (int c = 0; c < 8; ++c) q[c] = xadd16(q[c]);
            #pragma unroll
            for (int c = 0; c < 8; ++c) q[c] = xadd32(q[c]);
            #pragma unroll
            for (int c = 0; c < 4; ++c) {
                vv2[c].x = __builtin_amdgcn_rcpf(q[2 * c + 0] + EPS);
                vv2[c].y = __builtin_amdgcn_rcpf(q[2 * c + 1] + EPS);
            }
        }

        // ---- epilogue: out = E .* (u v^T) ----
        float4* __restrict__ o = (float4*)(out + (size_t)mat * 4096);
        #pragma unroll
        for (int r = 0; r < 8; ++r) {
            v2f u2 = (r & 1) ? (v2f){uu2[r >> 1].y, uu2[r >> 1].y}
                             : (v2f){uu2[r >> 1].x, uu2[r >> 1].x};
            v2f w0 = pk_mul(b2[r][0], pk_mul(vv2[0], u2));
            v2f w1 = pk_mul(b2[r][1], pk_mul(vv2[1], u2));
            v2f w2 = pk_mul(b2[r][2], pk_mul(vv2[2], u2));
            v2f w3 = pk_mul(b2[r][3], pk_mul(vv2[3], u2));
            float4 lo, hi;
            lo.x = w0.x; lo.y = w0.y; lo.z = w1.x; lo.w = w1.y;
            hi.x = w2.x; hi.y = w2.y; hi.z = w3.x; hi.w = w3.y;
            o[(8 * bi + r) * 16 + 2 * bj + 0] = lo;
            o[(8 * bi + r) * 16 + 2 * bj + 1] = hi;
        }
    }
}

extern "C" void kernel_launch(void* const* d_in, const int* in_sizes, int n_in,
                              void* d_out, int out_size, void* d_ws, size_t ws_size,
                              hipStream_t stream) {
    const float* x = (const float*)d_in[0];
    float* out = (float*)d_out;
    const int nmat = in_sizes[0] / 4096;                  // 8192 matrices of 64x64
    const int blocks = (nmat + 2 * MPW - 1) / (2 * MPW);  // 2 waves/block x MPW mats -> 1024
    sinkhorn_kernel<<<blocks, 128, 0, stream>>>(x, out, nmat);
}